// Round 28
// baseline (1654.411 us; speedup 1.0000x reference)
//
#include <hip/hip_runtime.h>

#define N_NODES 16384
#define N_EDGES 65536
#define N_GRAPHS 64
#define HID 768
#define DDIM 256
#define HEADS 4

typedef __attribute__((ext_vector_type(8))) short bf16x8;   // 8 bf16 = 4 VGPR (MFMA A/B frag)
typedef __attribute__((ext_vector_type(4))) float f32x4;    // MFMA C/D frag
typedef __attribute__((ext_vector_type(8))) unsigned short u16x8;

#define GLL(SRC, DST) __builtin_amdgcn_global_load_lds( \
    (const __attribute__((address_space(1))) void*)(SRC), \
    (__attribute__((address_space(3))) void*)(DST), 16, 0, 0)

// ---------- helpers ----------
__device__ __forceinline__ float wave_reduce_sum(float v) {
#pragma unroll
    for (int off = 32; off; off >>= 1) v += __shfl_xor(v, off);
    return v;
}

__device__ __forceinline__ unsigned short f2bf(float f) {   // RNE fp32 -> bf16 bits
    unsigned u = __float_as_uint(f);
    return (unsigned short)((u + 0x7fffu + ((u >> 16) & 1u)) >> 16);
}
__device__ __forceinline__ float bf2f(unsigned short h) {
    return __uint_as_float((unsigned)h << 16);
}

// ---------- fused cosine relevance + bf16 node features + edge histogram
//            + LAST-BLOCK scan/gbounds (dispatch fusion; device-scope atomics) ----------
__global__ __launch_bounds__(256) void relnf_kernel(
        const float* __restrict__ text, const float* __restrict__ nodex,
        const int* __restrict__ bid, const int* __restrict__ dst,
        unsigned short* __restrict__ nfs, int* __restrict__ cnt,
        int* __restrict__ base, int* __restrict__ cursor,
        int* __restrict__ gstart, int* __restrict__ flags) {
    int n = blockIdx.x, t = threadIdx.x;
    if (t < 4) atomicAdd(&cnt[dst[4 * n + t]], 1);      // fused hist
    const float* xr = nodex + (size_t)n * HID;
    const float* tr = text + (size_t)bid[n] * HID;
    float xv[3];
    float num = 0.f, tt = 0.f, xx = 0.f;
#pragma unroll
    for (int j = 0; j < 3; j++) {
        int c = t + j * 256;
        float a = xr[c], b = tr[c];
        xv[j] = a; num += a * b; tt += b * b; xx += a * a;
    }
    num = wave_reduce_sum(num);
    tt = wave_reduce_sum(tt);
    xx = wave_reduce_sum(xx);
    __shared__ float s0[4], s1[4], s2[4];
    int lane = t & 63, wv = t >> 6;
    if (lane == 0) { s0[wv] = num; s1[wv] = tt; s2[wv] = xx; }
    __syncthreads();
    num = s0[0] + s0[1] + s0[2] + s0[3];
    tt  = s1[0] + s1[1] + s1[2] + s1[3];
    xx  = s2[0] + s2[1] + s2[2] + s2[3];
    float r = num / fmaxf(sqrtf(tt) * sqrtf(xx), 1e-8f);
    unsigned short* o = nfs + (size_t)n * 1536;
#pragma unroll
    for (int j = 0; j < 3; j++) {
        int c = t + j * 256;
        o[c] = f2bf(xv[j] * r);
    }

    // ---- last-block scan + gbounds (was scan_kernel) ----
    __threadfence();
    __shared__ int lastf;
    if (t == 0) lastf = (atomicAdd(&flags[0], 1) == N_NODES - 1);
    __syncthreads();
    if (!lastf) return;
    if (t <= 64) {              // gbounds (binary search on sorted bid; plain input)
        int lo = 0, hi = N_NODES;
        while (lo < hi) { int mid = (lo + hi) >> 1; if (bid[mid] < t) lo = mid + 1; else hi = mid; }
        gstart[t] = lo;
    }
    int s = 0;
    for (int i = 0; i < 64; i++) s += atomicAdd(&cnt[t * 64 + i], 0);   // coherent read
    __shared__ int pref[256];
    pref[t] = s;
    __syncthreads();
    if (t == 0) {
        int a = 0;
        for (int i = 0; i < 256; i++) { int v = pref[i]; pref[i] = a; a += v; }
    }
    __syncthreads();
    int run = pref[t];
    for (int i = 0; i < 64; i++) {
        int v = atomicAdd(&cnt[t * 64 + i], 0);
        base[t * 64 + i] = run;
        cursor[t * 64 + i] = run;
        run += v;
    }
}

// ---------- MEGA prep kernel (block-range dispatch; all parts independent) ----------
// [0,12):       Wp^T tile  -> Wps hi block only (proj is 1-term)
// [12,44):      Wv^T tiles -> Wall rows 1024..2047
// [44,52):      Ws^T tiles -> Wall rows 2048..2303
// [52,2100):    w1 reduce  -> ballY[0..1023] per layer (coalesced reads)
// [2100,2132):  mker       -> Wall rows 0..1023 = M^T per layer/head (MFMA)
// [2132,2196):  tp         -> tp64[g]
// [2196,2212):  zero cnt (16384 ints)
// [2212,2245):  zero pstruct|psem|semden (32832 floats)
// [2245,2253):  bv copy -> ballY[1024..2047]
// [2253,2255):  bs copy -> ballY[2048..2303]
// [2255,2256):  zero flags (done-counters for relnf-scan / pool-clf)
__global__ __launch_bounds__(256, 2) void prep_mega(
        const float* __restrict__ Wp, const float* __restrict__ Wq,
        const float* __restrict__ Wk, const float* __restrict__ Wv,
        const float* __restrict__ Ws, const float* __restrict__ bq,
        const float* __restrict__ bk, const float* __restrict__ bv,
        const float* __restrict__ bs, const float* __restrict__ text,
        const float* __restrict__ bp,
        unsigned short* __restrict__ Wps, unsigned short* __restrict__ Wall,
        float* __restrict__ ballY, float* __restrict__ tp64,
        int* __restrict__ cnt, float* __restrict__ pzero,
        int* __restrict__ flags) {
    __shared__ unsigned short sb[17408];        // 34816B: transpose tile / mker As|Bs / tp row
    const int b = blockIdx.x, t = threadIdx.x;

    if (b < 52) {               // ---- LDS tile transposes (coalesced both sides) ----
        const float* S; unsigned short* D; int srcStride, dstStride;
        if (b < 12) {           // Wp [768,256] -> Wps hi block
            int kt = b >> 2, ct = b & 3, c0 = ct * 64;
            S = Wp + (size_t)kt * 256 * 256 + c0;
            D = Wps + (size_t)c0 * 2304 + kt * 256;
            srcStride = 256; dstStride = 2304;
        } else if (b < 44) {    // Wv [256,1024] -> Wall rows 1024+col
            int m = b - 12, L = m >> 4, ct = m & 15, c0 = ct * 64;
            S = Wv + (size_t)L * DDIM * 1024 + c0;
            D = Wall + (size_t)L * 2304 * 256 + (size_t)(1024 + c0) * 256;
            srcStride = 1024; dstStride = 256;
        } else {                // Ws [256,256] -> Wall rows 2048+col
            int m = b - 44, L = m >> 2, ct = m & 3, c0 = ct * 64;
            S = Ws + (size_t)L * DDIM * DDIM + c0;
            D = Wall + (size_t)L * 2304 * 256 + (size_t)(2048 + c0) * 256;
            srcStride = 256; dstStride = 256;
        }
        int lr = t >> 4, l16 = t & 15;
#pragma unroll
        for (int it = 0; it < 16; it++) {
            int r = it * 16 + lr;
            float4 v = ((const float4*)(S + (size_t)r * srcStride))[l16];
            *(ushort4*)&sb[r * 68 + l16 * 4] =
                make_ushort4(f2bf(v.x), f2bf(v.y), f2bf(v.z), f2bf(v.w));
        }
        __syncthreads();
        int c = t >> 2, part = t & 3;
        unsigned short* drow = D + (size_t)c * dstStride;
#pragma unroll
        for (int jj = 0; jj < 8; jj++) {
            int kbase = jj * 32 + part * 8;
            u16x8 tv;
#pragma unroll
            for (int i = 0; i < 8; i++) tv[i] = sb[(kbase + i) * 68 + c];
            *(u16x8*)(drow + kbase) = tv;
        }
    } else if (b < 2100) {      // ---- w1 reduce (coalesced) ----
        float* red = (float*)sb;
        int m = b - 52;
        int L = m >> 10, mm = m & 1023;
        int h = mm >> 8, bcol = mm & 255;
        const float* Wk_ = Wk + (size_t)L * DDIM * 1024;
        const float* bq_ = bq + L * 1024;
        float* bl = ballY + L * 2304;
        int lane = t & 63, wv = t >> 6;
        float v = Wk_[(size_t)bcol * 1024 + h * 256 + t] * bq_[h * 256 + t];
        v = wave_reduce_sum(v);
        if (lane == 0) red[wv] = v;
        __syncthreads();
        if (t == 0) bl[mm] = red[0] + red[1] + red[2] + red[3];
    } else if (b < 2132) {      // ---- mker: M^T = Wk_h @ Wq_h^T ----
        unsigned short* As_ = sb;
        unsigned short* Bs_ = sb + 8192;
        int m = b - 2100;
        const int bx = m & 1, by = (m >> 1) & 1, z = m >> 2;
        const int L = z >> 2, h = z & 3;
        const int lane = t & 63, wave = t >> 6;
        const int wm = wave >> 1, wn = wave & 1;
        const int row0 = by * 128, col0 = bx * 128;
        const float* Aq = Wk + (size_t)L * DDIM * 1024;     // rows = k-side
        const float* Ak = Wq + (size_t)L * DDIM * 1024;     // cols = q-side
        unsigned short* Wl = Wall + (size_t)L * 2304 * 256;
        const int l15 = lane & 15, l16 = lane >> 4;
        f32x4 acc[4][4] = {};
        int sr = t >> 1, scc = (t & 1) * 32;
        for (int k0 = 0; k0 < 256; k0 += 64) {
            __syncthreads();
            {
                const float* pa = Aq + (size_t)(row0 + sr) * 1024 + h * 256 + k0 + scc;
                const float* pb = Ak + (size_t)(col0 + sr) * 1024 + h * 256 + k0 + scc;
                unsigned short* da = As_ + sr * 64 + scc;
                unsigned short* db = Bs_ + sr * 64 + scc;
#pragma unroll
                for (int j = 0; j < 8; j++) {
                    float4 va = ((const float4*)pa)[j];
                    float4 vb2 = ((const float4*)pb)[j];
                    ((ushort4*)da)[j] = make_ushort4(f2bf(va.x), f2bf(va.y), f2bf(va.z), f2bf(va.w));
                    ((ushort4*)db)[j] = make_ushort4(f2bf(vb2.x), f2bf(vb2.y), f2bf(vb2.z), f2bf(vb2.w));
                }
            }
            __syncthreads();
#pragma unroll
            for (int kk = 0; kk < 2; kk++) {
                bf16x8 af[4], bfr[4];
#pragma unroll
                for (int f = 0; f < 4; f++) {
                    af[f]  = *(const bf16x8*)(As_ + ((wm * 64 + f * 16 + l15) * 64 + kk * 32 + l16 * 8));
                    bfr[f] = *(const bf16x8*)(Bs_ + ((wn * 64 + f * 16 + l15) * 64 + kk * 32 + l16 * 8));
                }
#pragma unroll
                for (int fi = 0; fi < 4; fi++)
#pragma unroll
                    for (int fj = 0; fj < 4; fj++)
                        acc[fi][fj] = __builtin_amdgcn_mfma_f32_16x16x32_bf16(
                            af[fi], bfr[fj], acc[fi][fj], 0, 0, 0);
            }
        }
#pragma unroll
        for (int fj = 0; fj < 4; fj++) {
            int cc = col0 + wn * 64 + fj * 16 + l15;
#pragma unroll
            for (int fi = 0; fi < 4; fi++) {
                int rbase2 = row0 + wm * 64 + fi * 16 + l16 * 4;
#pragma unroll
                for (int r = 0; r < 4; r++)
                    Wl[(size_t)(h * 256 + rbase2 + r) * 256 + cc] = f2bf(acc[fi][fj][r]);
            }
        }
    } else if (b < 2196) {      // ---- tp (text projection, one block per graph) ----
        float* trow = (float*)sb;               // 3KB alias
        int g = b - 2132;
#pragma unroll
        for (int j = 0; j < 3; j++) trow[t + j * 256] = text[(size_t)g * 768 + t + j * 256];
        __syncthreads();
        float acc = bp[t];
#pragma unroll 4
        for (int k = 0; k < 768; k++) acc += trow[k] * Wp[(size_t)k * 256 + t];
        tp64[(size_t)g * 256 + t] = acc;
    } else if (b < 2212) {      // ---- zero cnt ----
        int i = (b - 2196) * 1024 + t * 4;
        ((int4*)(cnt + i))[0] = make_int4(0, 0, 0, 0);
    } else if (b < 2245) {      // ---- zero pstruct|psem|semden (32832 floats) ----
        int i = (b - 2212) * 1024 + t * 4;
        if (i < 32832)
            ((float4*)(pzero + i))[0] = make_float4(0.f, 0.f, 0.f, 0.f);
    } else if (b < 2253) {      // ---- bv copy ----
        int m = b - 2245, L = m >> 2, chunk = m & 3;
        int i = chunk * 256 + t;
        (ballY + (size_t)L * 2304)[1024 + i] = (bv + (size_t)L * 1024)[i];
    } else if (b < 2255) {      // ---- bs copy ----
        int L = b - 2253;
        (ballY + (size_t)L * 2304)[2048 + t] = (bs + (size_t)L * 256)[t];
    } else {                    // ---- zero done-flags ----
        if (t < 8) flags[t] = 0;
    }
}

// ---------- XCD-chunked block swizzle (m204 bijective) ----------
__device__ __forceinline__ void swz_block(int& bx, int& by) {
    int nwg = gridDim.x * gridDim.y;
    int lin = blockIdx.y * gridDim.x + blockIdx.x;
    int qd = nwg >> 3, rr = nwg & 7;
    int xcd = lin & 7, j = lin >> 3;
    int wg = (xcd < rr ? xcd * (qd + 1) : rr * (qd + 1) + (xcd - rr) * qd) + j;
    bx = wg % gridDim.x;
    by = wg / gridDim.x;
}

// ---------- MERGED scatter (CSR build) + proj GEMM, block-range dispatch ----------
// [0,256):    scatter (atomic cursor)
// [256,1280): proj 64x64 tiles, 1-TERM (Ahi@Bhi), dbuf, rule-#21 swizzle
__global__ __launch_bounds__(256, 4) void scatter_proj(
        const int* __restrict__ src, const int* __restrict__ dst,
        int* __restrict__ cursor, int* __restrict__ esrc,
        const unsigned short* __restrict__ A, const unsigned short* __restrict__ B,
        const float* __restrict__ bias, float* __restrict__ x,
        unsigned short* __restrict__ xb) {
    __shared__ unsigned short As[2][4096];
    __shared__ unsigned short Bs[2][4096];
    const int tid = threadIdx.x;
    if (blockIdx.x < 256) {     // ---- scatter ----
        int e = blockIdx.x * 256 + tid;
        int d = dst[e];
        int pos = atomicAdd(&cursor[d], 1);
        esrc[pos] = src[e];
        return;
    }
    // ---- proj (1024 logical blocks over 4x256 tile grid, XCD-chunked) ----
    int lin = blockIdx.x - 256;
    int wg = (lin & 7) * 128 + (lin >> 3);      // nwg=1024: qd=128, rr=0
    int bx = wg & 3, by = wg >> 2;
    const int lane = tid & 63, wave = tid >> 6;
    const int wm = wave >> 1, wn = wave & 1;
    const int row0 = by * 64, col0 = bx * 64;
    const int l15 = lane & 15, l16 = lane >> 4;
    f32x4 acc[2][2] = {};
    const char* Ac = (const char*)A;
    const char* Bc = (const char*)B;

#define PSTAGE(BUF, T) do { \
    int k_ = (T) * 128; \
    _Pragma("unroll") \
    for (int i_ = 0; i_ < 2; i_++) { \
        int o_ = i_ * 4096 + tid * 16; \
        int r_ = o_ >> 7, cb_ = o_ & 127; \
        int cs_ = cb_ ^ ((r_ & 7) << 4); \
        GLL(Ac + (size_t)(row0 + r_) * 3072 + k_ + cs_, (char*)As[BUF] + o_); \
        GLL(Bc + (size_t)(col0 + r_) * 4608 + k_ + cs_, (char*)Bs[BUF] + o_); \
    } } while (0)

#define PCOMPUTE(BUF) do { \
    _Pragma("unroll") \
    for (int kk = 0; kk < 2; kk++) { \
        bf16x8 af[2], bfr[2]; \
        _Pragma("unroll") \
        for (int f = 0; f < 2; f++) { \
            int rowa_ = wm * 32 + f * 16 + l15; \
            int qba_ = (kk * 64 + l16 * 16) ^ ((rowa_ & 7) << 4); \
            af[f]  = *(const bf16x8*)((const char*)As[BUF] + rowa_ * 128 + qba_); \
            int rowb_ = wn * 32 + f * 16 + l15; \
            int qbb_ = (kk * 64 + l16 * 16) ^ ((rowb_ & 7) << 4); \
            bfr[f] = *(const bf16x8*)((const char*)Bs[BUF] + rowb_ * 128 + qbb_); \
        } \
        _Pragma("unroll") \
        for (int fi = 0; fi < 2; fi++) \
            _Pragma("unroll") \
            for (int fj = 0; fj < 2; fj++) \
                acc[fi][fj] = __builtin_amdgcn_mfma_f32_16x16x32_bf16( \
                    af[fi], bfr[fj], acc[fi][fj], 0, 0, 0); \
    } } while (0)

    PSTAGE(0, 0);
    __syncthreads();
    for (int t = 0; t < 12; t += 2) {
        PSTAGE(1, t + 1);
        PCOMPUTE(0); __syncthreads();
        if (t + 2 < 12) PSTAGE(0, t + 2);
        PCOMPUTE(1); __syncthreads();
    }
#undef PSTAGE
#undef PCOMPUTE
    // staged coalesced epilogue (f32 + bf16)
    float* smemf = (float*)&As[0][0];   // 64x64 f32 = 16KB
#pragma unroll
    for (int fj = 0; fj < 2; fj++) {
        int cl = wn * 32 + fj * 16 + l15;
        float bb = bias[col0 + cl];
#pragma unroll
        for (int fi = 0; fi < 2; fi++)
#pragma unroll
            for (int r = 0; r < 4; r++) {
                int rl = wm * 32 + fi * 16 + l16 * 4 + r;
                int c16 = cl >> 2;
                smemf[rl * 64 + ((c16 ^ (rl & 15)) << 2) + (cl & 3)] = acc[fi][fj][r] + bb;
            }
    }
    __syncthreads();
    int rl = tid >> 2, q = tid & 3;
#pragma unroll
    for (int i = 0; i < 4; i++) {
        int c16 = q * 4 + i;
        float4 v4 = *(const float4*)&smemf[rl * 64 + ((c16 ^ (rl & 15)) << 2)];
        *(float4*)(x + (size_t)(row0 + rl) * 256 + col0 + c16 * 4) = v4;
        *(ushort4*)(xb + (size_t)(row0 + rl) * 256 + col0 + c16 * 4) =
            make_ushort4(f2bf(v4.x), f2bf(v4.y), f2bf(v4.z), f2bf(v4.w));
    }
}

// ---------- fused YD/v/skip GEMM: [16384,2304] = xin @ Wall^T, 64x64 tiles ----------
// 8 blocks/CU (wave cap), max TLP. Rotation swizzle C-stage (2-way aliasing, free).
__global__ __launch_bounds__(256, 8) void gemm_yvs64t(
        const unsigned short* __restrict__ A, const unsigned short* __restrict__ B,
        const float* __restrict__ ball,
        unsigned short* __restrict__ Yb, unsigned short* __restrict__ vb,
        unsigned short* __restrict__ hb) {
    __shared__ unsigned short smem[8192];       // As(8KB) | Bs(8KB); C-stage reuses 8KB
    unsigned short* As = smem;
    unsigned short* Bs = smem + 4096;
    int bx, by; swz_block(bx, by);
    const int tid = threadIdx.x;
    const int lane = tid & 63, wave = tid >> 6;
    const int wm = wave >> 1, wn = wave & 1;    // 2x2 waves: 32 rows x 32 cols each
    const int row0 = by * 64, col0 = bx * 64;
    const int l15 = lane & 15, l16 = lane >> 4;
    f32x4 acc[2][2] = {};
    const char* Ac = (const char*)A;
    const char* Bc = (const char*)B;

    for (int k0 = 0; k0 < 256; k0 += 64) {
        __syncthreads();
#pragma unroll
        for (int i = 0; i < 2; i++) {           // A+B tiles 8KB each, src pre-swizzled
            int o = i * 4096 + tid * 16;
            int r = o >> 7, cb = o & 127;
            int cs = cb ^ ((r & 7) << 4);
            GLL(Ac + (size_t)(row0 + r) * 512 + k0 * 2 + cs, (char*)As + o);
            GLL(Bc + (size_t)(col0 + r) * 512 + k0 * 2 + cs, (char*)Bs + o);
        }
        __syncthreads();
#pragma unroll
        for (int kk = 0; kk < 2; kk++) {
            bf16x8 af[2], bfr[2];
#pragma unroll
            for (int f = 0; f < 2; f++) {
                int rowa = wm * 32 + f * 16 + l15;
                int qba = (kk * 64 + l16 * 16) ^ ((rowa & 7) << 4);
                af[f] = *(const bf16x8*)((const char*)As + rowa * 128 + qba);
                int rowb = wn * 32 + f * 16 + l15;
                int qbb = (kk * 64 + l16 * 16) ^ ((rowb & 7) << 4);
                bfr[f] = *(const bf16x8*)((const char*)Bs + rowb * 128 + qbb);
            }
#pragma unroll
            for (int fi = 0; fi < 2; fi++)
#pragma unroll
                for (int fj = 0; fj < 2; fj++)
                    acc[fi][fj] = __builtin_amdgcn_mfma_f32_16x16x32_bf16(
                        af[fi], bfr[fj], acc[fi][fj], 0, 0, 0);
        }
    }
    __syncthreads();
    // stage bf16 C-tile (64x64) to LDS with 8-chunk rotation swizzle
#pragma unroll
    for (int fj = 0; fj < 2; fj++) {
        int cl = wn * 32 + fj * 16 + l15;       // local col 0..63
        float bb = ball[col0 + cl];
#pragma unroll
        for (int fi = 0; fi < 2; fi++)
#pragma unroll
            for (int r = 0; r < 4; r++) {
                int rl = wm * 32 + fi * 16 + l16 * 4 + r;   // local row 0..63
                int chunk = ((cl >> 3) + rl) & 7;
                smem[rl * 64 + chunk * 8 + (cl & 7)] = f2bf(acc[fi][fj][r] + bb);
            }
    }
    __syncthreads();
    // coalesced store: 4 threads cover one 128B row
    int rl = tid >> 2, part = tid & 3;
    unsigned short* dstp;
    if (bx < 16)      dstp = Yb + (size_t)(row0 + rl) * 1024 + col0 + part * 16;
    else if (bx < 32) dstp = vb + (size_t)(row0 + rl) * 1024 + (col0 - 1024) + part * 16;
    else              dstp = hb + (size_t)(row0 + rl) * 256 + (col0 - 2048) + part * 16;
#pragma unroll
    for (int i = 0; i < 2; i++) {
        int chunk = (part * 2 + i + rl) & 7;
        ((u16x8*)dstp)[i] = *(const u16x8*)(smem + rl * 64 + chunk * 8);
    }
}

// ---------- fused per-node: scores (YD_d . x_s)/16 + TWO-CHAIN single-pass online
//            softmax + alpha*v gather + head-mean + skip (+resid) + LN + ReLU ----------
template<bool RESID, bool WXB>
__global__ __launch_bounds__(256) void agg_norm_fused(
        const unsigned short* __restrict__ vb, const unsigned short* __restrict__ Yb,
        const int* __restrict__ base, const int* __restrict__ cnt,
        const int* __restrict__ esrc, const unsigned short* __restrict__ hb,
        float* __restrict__ x, const unsigned short* __restrict__ xin,
        unsigned short* __restrict__ xout,
        const float* __restrict__ gamma, const float* __restrict__ beta) {
    __shared__ float hacc[4][256];
    __shared__ float tmp[4];
    // bijective XCD-chunk remap (N_NODES % 8 == 0)
    int n = (blockIdx.x & 7) * (N_NODES >> 3) + (blockIdx.x >> 3);
    int tid = threadIdx.x, lane = tid & 63, h = tid >> 6;
    int start = base[n], deg = cnt[n];

    // own YD row segment (head h), 4 channels per lane
    ushort4 ya = ((const ushort4*)(Yb + (size_t)n * 1024 + h * 256))[lane];
    float y0 = bf2f(ya.x), y1 = bf2f(ya.y), y2 = bf2f(ya.z), y3 = bf2f(ya.w);

    float m0 = -1e30f, den0 = 0.f, m1 = -1e30f, den1 = 0.f;
    float4 acc0 = {0.f, 0.f, 0.f, 0.f}, acc1 = {0.f, 0.f, 0.f, 0.f};
    ushort4 xsA = {0, 0, 0, 0}, vvA = {0, 0, 0, 0};
    ushort4 xsB = {0, 0, 0, 0}, vvB = {0, 0, 0, 0};
    if (deg > 0) {
        int s = esrc[start];
        xsA = ((const ushort4*)(xin + (size_t)s * 256))[lane];
        vvA = ((const ushort4*)(vb + (size_t)s * 1024 + h * 256))[lane];
    }
    if (deg > 1) {
        int s = esrc[start + 1];
        xsB = ((const ushort4*)(xin + (size_t)s * 256))[lane];
        vvB = ((const ushort4*)(vb + (size_t)s * 1024 + h * 256))[lane];
    }
    for (int i = 0; i < deg; i += 2) {
        ushort4 xsA_n = xsA, vvA_n = vvA, xsB_n = xsB, vvB_n = vvB;
        if (i + 2 < deg) {      // prefetch next pair before the reduce chains
            int s = esrc[start + i + 2];
            xsA_n = ((const ushort4*)(xin + (size_t)s * 256))[lane];
            vvA_n = ((const ushort4*)(vb + (size_t)s * 1024 + h * 256))[lane];
        }
        if (i + 3 < deg) {
            int s = esrc[start + i + 3];
            xsB_n = ((const ushort4*)(xin + (size_t)s * 256))[lane];
            vvB_n = ((const ushort4*)(vb + (size_t)s * 1024 + h * 256))[lane];
        }
        float p0 = y0 * bf2f(xsA.x) + y1 * bf2f(xsA.y)
                 + y2 * bf2f(xsA.z) + y3 * bf2f(xsA.w);
        float p1 = y0 * bf2f(xsB.x) + y1 * bf2f(xsB.y)
                 + y2 * bf2f(xsB.z) + y3 * bf2f(xsB.w);
        // two independent butterfly reduces (interleave in the pipe)
#pragma unroll
        for (int off = 32; off; off >>= 1) {
            p0 += __shfl_xor(p0, off);
            p1 += __shfl_xor(p1, off);
        }
        p0 *= 0.0625f; p1 *= 0.0625f;
        // chain 0 (edge i, always valid)
        if (p0 > m0) {
            float sc_ = __expf(m0 - p0);
            den0 = den0 * sc_ + 1.0f;
            acc0.x = acc0.x * sc_ + bf2f(vvA.x);
            acc0.y = acc0.y * sc_ + bf2f(vvA.y);
            acc0.z = acc0.z * sc_ + bf2f(vvA.z);
            acc0.w = acc0.w * sc_ + bf2f(vvA.w);
            m0 = p0;
        } else {
            float a = __expf(p0 - m0);
            den0 += a;
            acc0.x += a * bf2f(vvA.x); acc0.y += a * bf2f(vvA.y);
            acc0.z += a * bf2f(vvA.z); acc0.w += a * bf2f(vvA.w);
        }
        // chain 1 (edge i+1; wave-uniform guard)
        if (i + 1 < deg) {
            if (p1 > m1) {
                float sc_ = __expf(m1 - p1);
                den1 = den1 * sc_ + 1.0f;
                acc1.x = acc1.x * sc_ + bf2f(vvB.x);
                acc1.y = acc1.y * sc_ + bf2f(vvB.y);
                acc1.z = acc1.z * sc_ + bf2f(vvB.z);
                acc1.w = acc1.w * sc_ + bf2f(vvB.w);
                m1 = p1;
            } else {
                float a = __expf(p1 - m1);
                den1 += a;
                acc1.x += a * bf2f(vvB.x); acc1.y += a * bf2f(vvB.y);
                acc1.z += a * bf2f(vvB.z); acc1.w += a * bf2f(vvB.w);
            }
        }
        xsA = xsA_n; vvA = vvA_n; xsB = xsB_n; vvB = vvB_n;
    }
    // exact merge of the two chains (finite sentinels: -1e30 keeps exp args finite)
    float mm = fmaxf(m0, m1);
    float e0 = __expf(m0 - mm), e1 = __expf(m1 - mm);
    float den = den0 * e0 + den1 * e1;
    float4 acc;
    acc.x = acc0.x * e0 + acc1.x * e1;
    acc.y = acc0.y * e0 + acc1.y * e1;
    acc.z = acc0.z * e0 + acc1.z * e1;
    acc.w = acc0.w * e0 + acc1.w * e1;
    float inv_den = 0.25f / (den + 1e-16f);     // fold head-mean
    acc.x *= inv_den; acc.y *= inv_den; acc.z *= inv_den; acc.w *= inv_den;
    ((float4*)&hacc[h][lane * 4])[0] = acc;
    __syncthreads();

    int c = tid;
    float val = hacc[0][c] + hacc[1][c] + hacc[2][c] + hacc[3][c]
              + bf2f(hb[(size_t)n * 256 + c]);
    if (RESID) val += x[(size_t)n * 256 + c];

    float s1 = wave_reduce_sum(val);
    if (lane == 0) tmp[h] = s1;
    __syncthreads();
    float mu = (tmp[0] + tmp[1] + tmp[2] + tmp[3]) * (1.0f / 256.0f);
    __syncthreads();
    float d = val - mu;
    float s2 = wave_reduce_sum(d * d);
    if (lane == 0) tmp[h] = s2;
    __syncthreads();
    float inv = rsqrtf((tmp[0] + tmp[1] + tmp[2] + tmp[3]) * (1.0f / 256.0f) + 1e-5f);
    float o = fmaxf(d * inv * gamma[c] + beta[c], 0.f);
    x[(size_t)n * 256 + c] = o;
    if (WXB) xout[(size_t)n * 256 + c] = f2bf(o);
}

// ---------- fused pooling + LAST-BLOCK classifier ----------
__global__ __launch_bounds__(256) void pool_clf(
        const float* __restrict__ x, const float* __restrict__ tp,
        const int* __restrict__ gstart, float* __restrict__ pstruct,
        float* __restrict__ psem, float* __restrict__ semden,
        const float* __restrict__ text, const float* __restrict__ w,
        const float* __restrict__ bcl, float* __restrict__ out,
        int* __restrict__ flags) {
    int g = blockIdx.x >> 2, q = blockIdx.x & 3;
    int s0 = gstart[g], s1 = gstart[g + 1];
    int chunk = (s1 - s0 + 3) >> 2;
    int a = s0 + q * chunk, b = min(a + chunk, s1);
    int wave = threadIdx.x >> 6, lane = threadIdx.x & 63;
    float4 tv = ((const float4*)(tp + (size_t)g * 256))[lane];
    float4 acc = {0.f, 0.f, 0.f, 0.f};
    float4 accs = {0.f, 0.f, 0.f, 0.f};
    float esum = 0.f;
    for (int n = a + wave; n < b; n += 4) {
        float4 xv = ((const float4*)(x + (size_t)n * 256))[lane];
        float p = wave_reduce_sum(xv.x * tv.x + xv.y * tv.y + xv.z * tv.z + xv.w * tv.w);
        float e = __expf(p);            // wave-uniform after reduce
        esum += e;
        acc.x += xv.x; acc.y += xv.y; acc.z += xv.z; acc.w += xv.w;
        accs.x += e * xv.x; accs.y += e * xv.y; accs.z += e * xv.z; accs.w += e * xv.w;
    }
    __shared__ float sacc[4][256];
    __shared__ float sacc2[4][256];
    __shared__ float tse[4];
    ((float4*)&sacc[wave][lane * 4])[0] = acc;
    ((float4*)&sacc2[wave][lane * 4])[0] = accs;
    if (lane == 0) tse[wave] = esum;
    __syncthreads();
    int c = threadIdx.x;
    float v = sacc[0][c] + sacc[1][c] + sacc[2][c] + sacc[3][c];
    float v2 = sacc2[0][c] + sacc2[1][c] + sacc2[2][c] + sacc2[3][c];
    atomicAdd(&pstruct[(size_t)g * 256 + c], v);
    atomicAdd(&psem[(size_t)g * 256 + c], v2);
    if (threadIdx.x == 0)
        atomicAdd(&semden[g], tse[0] + tse[1] + tse[2] + tse[3]);

    // ---- last-block classifier (was clf_kernel); coherent reads via atomicAdd(p,0) ----
    __threadfence();
    __shared__ int lastp;
    if (threadIdx.x == 0) lastp = (atomicAdd(&flags[1], 1) == (int)gridDim.x - 1);
    __syncthreads();
    if (!lastp) return;
    for (int gi = 0; gi < 16; gi++) {
        int gg = wave * 16 + gi;
        float invc = 1.0f / fmaxf((float)(gstart[gg + 1] - gstart[gg]), 1.0f);
        float invs = 1.0f / (atomicAdd(&semden[gg], 0.0f) + 1e-8f);
        float accl = 0.f;
#pragma unroll
        for (int i = 0; i < 4; i++) {
            int cc = lane + i * 64;
            accl += atomicAdd(&pstruct[(size_t)gg * 256 + cc], 0.0f) * invc * w[cc];
        }
#pragma unroll
        for (int i = 0; i < 4; i++) {
            int cc = lane + i * 64;
            accl += atomicAdd(&psem[(size_t)gg * 256 + cc], 0.0f) * invs * w[256 + cc];
        }
#pragma unroll
        for (int i = 0; i < 12; i++) {
            int cc = lane + i * 64;
            accl += text[(size_t)gg * 768 + cc] * w[512 + cc];
        }
        accl = wave_reduce_sum(accl);
        if (lane == 0) out[gg] = accl + bcl[0];
    }
}

extern "C" void kernel_launch(void* const* d_in, const int* in_sizes, int n_in,
                              void* d_out, int out_size, void* d_ws, size_t ws_size,
                              hipStream_t stream) {
    const float* text  = (const float*)d_in[0];
    const float* nodex = (const float*)d_in[1];
    const float* Wp    = (const float*)d_in[2];
    const float* bp    = (const float*)d_in[3];
    const float* Wq    = (const float*)d_in[4];
    const float* bq    = (const float*)d_in[5];
    const float* Wk    = (const float*)d_in[6];
    const float* bk    = (const float*)d_in[7];
    const float* Wv    = (const float*)d_in[8];
    const float* bv    = (const float*)d_in[9];
    const float* Ws    = (const float*)d_in[10];
    const float* bs    = (const float*)d_in[11];
    const float* gamma = (const float*)d_in[12];
    const float* beta  = (const float*)d_in[13];
    const float* clfw  = (const float*)d_in[14];
    const float* clfb  = (const float*)d_in[15];
    const int*   eidx  = (const int*)d_in[16];
    const int*   bid   = (const int*)d_in[17];
    const int* src = eidx;
    const int* dst = eidx + N_EDGES;
    float* out = (float*)d_out;

    // workspace layout
    float* x     = (float*)d_ws;                     // 16384*256 f32
    float* tp64  = x + (size_t)N_NODES * 256;        // 64*256
    float* pstruct = tp64 + 64 * 256;                // 64*256
    float* psem  = pstruct + 64 * 256;               // 64*256
    float* semden = psem + 64 * 256;                 // 64
    float* ballY = semden + 64;                      // 2*2304
    int* esrc    = (int*)(ballY + 2 * 2304);         // 65536
    int* cnt     = esrc + N_EDGES;                   // 16384
    int* base    = cnt + N_NODES;                    // 16384
    int* cursor  = base + N_NODES;                   // 16384
    int* gstart  = cursor + N_NODES;                 // 80 (65 used)
    int* flags   = gstart + 80;                      // 8 (done-counters)
    unsigned short* Yb   = (unsigned short*)(flags + 8);    // 16384*1024 bf16
    unsigned short* vb   = Yb + (size_t)N_NODES * 1024;     // 16384*1024
    unsigned short* hb   = vb + (size_t)N_NODES * 1024;     // 16384*256
    unsigned short* xb   = hb + (size_t)N_NODES * 256;      // 16384*256
    unsigned short* xb2  = xb + (size_t)N_NODES * 256;      // 16384*256 (layer-1 input)
    unsigned short* Wall = xb2 + (size_t)N_NODES * 256;     // 2*2304*256
    unsigned short* Wps  = Wall + (size_t)2 * 2304 * 256;   // 256*2304
    // nfs [16384,1536] aliases Yb(+part of vb); consumed by proj before those are written
    unsigned short* nfs = Yb;

    // MEGA prep: Wps + Wall/ballY + M^T + tp64 + zero(cnt/pools/flags) in ONE dispatch
    prep_mega<<<2256, 256, 0, stream>>>(Wp, Wq, Wk, Wv, Ws, bq, bk, bv, bs, text, bp,
                                        Wps, Wall, ballY, tp64, cnt, pstruct, flags);
    // relevance + node features + edge histogram + LAST-BLOCK scan/gbounds
    relnf_kernel<<<N_NODES, 256, 0, stream>>>(text, nodex, bid, dst, nfs, cnt,
                                              base, cursor, gstart, flags);
    // merged scatter (CSR) + projection GEMM (emits x f32 + xb bf16)
    scatter_proj<<<1280, 256, 0, stream>>>(src, dst, cursor, esrc,
                                           nfs, Wps, bp, x, xb);

    for (int i = 0; i < 2; i++) {
        const unsigned short* xin = (i == 0) ? xb : xb2;
        // fused YD/v/skip GEMM (K=256, 64x64 tiles, 8 blocks/CU, rotation-swizzled C-stage)
        gemm_yvs64t<<<dim3(36, N_NODES / 64), 256, 0, stream>>>(
            xin, Wall + (size_t)i * 2304 * 256, ballY + i * 2304, Yb, vb, hb);
        // fused scores + two-chain softmax + gather + head-mean + skip + (resid) + LN + ReLU
        if (i == 0)
            agg_norm_fused<true, true><<<N_NODES, 256, 0, stream>>>(
                vb, Yb, base, cnt, esrc, hb, x, xin, xb2, gamma, beta);
        else
            agg_norm_fused<false, false><<<N_NODES, 256, 0, stream>>>(
                vb, Yb, base, cnt, esrc, hb, x, xin, xb2, gamma + 256, beta + 256);
    }

    // fused pool + LAST-BLOCK classifier (pools/flags zeroed by prep_mega)
    pool_clf<<<N_GRAPHS * 4, 256, 0, stream>>>(x, tp64, gstart, pstruct, psem, semden,
                                               text, clfw, clfb, out, flags);
}

// Round 29
// 299.039 us; speedup vs baseline: 5.5324x; 5.5324x over previous
//
#include <hip/hip_runtime.h>

#define N_NODES 16384
#define N_EDGES 65536
#define N_GRAPHS 64
#define HID 768
#define DDIM 256
#define HEADS 4

typedef __attribute__((ext_vector_type(8))) short bf16x8;   // 8 bf16 = 4 VGPR (MFMA A/B frag)
typedef __attribute__((ext_vector_type(4))) float f32x4;    // MFMA C/D frag
typedef __attribute__((ext_vector_type(8))) unsigned short u16x8;

#define GLL(SRC, DST) __builtin_amdgcn_global_load_lds( \
    (const __attribute__((address_space(1))) void*)(SRC), \
    (__attribute__((address_space(3))) void*)(DST), 16, 0, 0)

// ---------- helpers ----------
__device__ __forceinline__ float wave_reduce_sum(float v) {
#pragma unroll
    for (int off = 32; off; off >>= 1) v += __shfl_xor(v, off);
    return v;
}

__device__ __forceinline__ unsigned short f2bf(float f) {   // RNE fp32 -> bf16 bits
    unsigned u = __float_as_uint(f);
    return (unsigned short)((u + 0x7fffu + ((u >> 16) & 1u)) >> 16);
}
__device__ __forceinline__ float bf2f(unsigned short h) {
    return __uint_as_float((unsigned)h << 16);
}

// ---------- fused cosine relevance + bf16 node features + edge histogram ----------
// R27 lesson: NO device-scope fence here — 16384 blocks x __threadfence() = 1.35ms.
__global__ __launch_bounds__(256) void relnf_kernel(
        const float* __restrict__ text, const float* __restrict__ nodex,
        const int* __restrict__ bid, const int* __restrict__ dst,
        unsigned short* __restrict__ nfs, int* __restrict__ cnt) {
    int n = blockIdx.x, t = threadIdx.x;
    if (t < 4) atomicAdd(&cnt[dst[4 * n + t]], 1);      // fused hist
    const float* xr = nodex + (size_t)n * HID;
    const float* tr = text + (size_t)bid[n] * HID;
    float xv[3];
    float num = 0.f, tt = 0.f, xx = 0.f;
#pragma unroll
    for (int j = 0; j < 3; j++) {
        int c = t + j * 256;
        float a = xr[c], b = tr[c];
        xv[j] = a; num += a * b; tt += b * b; xx += a * a;
    }
    num = wave_reduce_sum(num);
    tt = wave_reduce_sum(tt);
    xx = wave_reduce_sum(xx);
    __shared__ float s0[4], s1[4], s2[4];
    int lane = t & 63, wv = t >> 6;
    if (lane == 0) { s0[wv] = num; s1[wv] = tt; s2[wv] = xx; }
    __syncthreads();
    num = s0[0] + s0[1] + s0[2] + s0[3];
    tt  = s1[0] + s1[1] + s1[2] + s1[3];
    xx  = s2[0] + s2[1] + s2[2] + s2[3];
    float r = num / fmaxf(sqrtf(tt) * sqrtf(xx), 1e-8f);
    unsigned short* o = nfs + (size_t)n * 1536;
#pragma unroll
    for (int j = 0; j < 3; j++) {
        int c = t + j * 256;
        o[c] = f2bf(xv[j] * r);
    }
}

// ---------- MEGA prep kernel (block-range dispatch; all parts independent) ----------
// [0,12):       Wp^T tile  -> Wps hi block only (proj is 1-term)
// [12,44):      Wv^T tiles -> Wall rows 1024..2047
// [44,52):      Ws^T tiles -> Wall rows 2048..2303
// [52,2100):    w1 reduce  -> ballY[0..1023] per layer (coalesced reads)
// [2100,2132):  mker       -> Wall rows 0..1023 = M^T per layer/head (MFMA)
// [2132,2196):  tp         -> tp64[g]
// [2196,2212):  zero cnt (16384 ints)
// [2212,2245):  zero pstruct|psem|semden (32832 floats)
// [2245,2253):  bv copy -> ballY[1024..2047]
// [2253,2255):  bs copy -> ballY[2048..2303]
__global__ __launch_bounds__(256, 2) void prep_mega(
        const float* __restrict__ Wp, const float* __restrict__ Wq,
        const float* __restrict__ Wk, const float* __restrict__ Wv,
        const float* __restrict__ Ws, const float* __restrict__ bq,
        const float* __restrict__ bk, const float* __restrict__ bv,
        const float* __restrict__ bs, const float* __restrict__ text,
        const float* __restrict__ bp,
        unsigned short* __restrict__ Wps, unsigned short* __restrict__ Wall,
        float* __restrict__ ballY, float* __restrict__ tp64,
        int* __restrict__ cnt, float* __restrict__ pzero) {
    __shared__ unsigned short sb[17408];        // 34816B: transpose tile / mker As|Bs / tp row
    const int b = blockIdx.x, t = threadIdx.x;

    if (b < 52) {               // ---- LDS tile transposes (coalesced both sides) ----
        const float* S; unsigned short* D; int srcStride, dstStride;
        if (b < 12) {           // Wp [768,256] -> Wps hi block
            int kt = b >> 2, ct = b & 3, c0 = ct * 64;
            S = Wp + (size_t)kt * 256 * 256 + c0;
            D = Wps + (size_t)c0 * 2304 + kt * 256;
            srcStride = 256; dstStride = 2304;
        } else if (b < 44) {    // Wv [256,1024] -> Wall rows 1024+col
            int m = b - 12, L = m >> 4, ct = m & 15, c0 = ct * 64;
            S = Wv + (size_t)L * DDIM * 1024 + c0;
            D = Wall + (size_t)L * 2304 * 256 + (size_t)(1024 + c0) * 256;
            srcStride = 1024; dstStride = 256;
        } else {                // Ws [256,256] -> Wall rows 2048+col
            int m = b - 44, L = m >> 2, ct = m & 3, c0 = ct * 64;
            S = Ws + (size_t)L * DDIM * DDIM + c0;
            D = Wall + (size_t)L * 2304 * 256 + (size_t)(2048 + c0) * 256;
            srcStride = 256; dstStride = 256;
        }
        int lr = t >> 4, l16 = t & 15;
#pragma unroll
        for (int it = 0; it < 16; it++) {
            int r = it * 16 + lr;
            float4 v = ((const float4*)(S + (size_t)r * srcStride))[l16];
            *(ushort4*)&sb[r * 68 + l16 * 4] =
                make_ushort4(f2bf(v.x), f2bf(v.y), f2bf(v.z), f2bf(v.w));
        }
        __syncthreads();
        int c = t >> 2, part = t & 3;
        unsigned short* drow = D + (size_t)c * dstStride;
#pragma unroll
        for (int jj = 0; jj < 8; jj++) {
            int kbase = jj * 32 + part * 8;
            u16x8 tv;
#pragma unroll
            for (int i = 0; i < 8; i++) tv[i] = sb[(kbase + i) * 68 + c];
            *(u16x8*)(drow + kbase) = tv;
        }
    } else if (b < 2100) {      // ---- w1 reduce (coalesced) ----
        float* red = (float*)sb;
        int m = b - 52;
        int L = m >> 10, mm = m & 1023;
        int h = mm >> 8, bcol = mm & 255;
        const float* Wk_ = Wk + (size_t)L * DDIM * 1024;
        const float* bq_ = bq + L * 1024;
        float* bl = ballY + L * 2304;
        int lane = t & 63, wv = t >> 6;
        float v = Wk_[(size_t)bcol * 1024 + h * 256 + t] * bq_[h * 256 + t];
        v = wave_reduce_sum(v);
        if (lane == 0) red[wv] = v;
        __syncthreads();
        if (t == 0) bl[mm] = red[0] + red[1] + red[2] + red[3];
    } else if (b < 2132) {      // ---- mker: M^T = Wk_h @ Wq_h^T ----
        unsigned short* As_ = sb;
        unsigned short* Bs_ = sb + 8192;
        int m = b - 2100;
        const int bx = m & 1, by = (m >> 1) & 1, z = m >> 2;
        const int L = z >> 2, h = z & 3;
        const int lane = t & 63, wave = t >> 6;
        const int wm = wave >> 1, wn = wave & 1;
        const int row0 = by * 128, col0 = bx * 128;
        const float* Aq = Wk + (size_t)L * DDIM * 1024;     // rows = k-side
        const float* Ak = Wq + (size_t)L * DDIM * 1024;     // cols = q-side
        unsigned short* Wl = Wall + (size_t)L * 2304 * 256;
        const int l15 = lane & 15, l16 = lane >> 4;
        f32x4 acc[4][4] = {};
        int sr = t >> 1, scc = (t & 1) * 32;
        for (int k0 = 0; k0 < 256; k0 += 64) {
            __syncthreads();
            {
                const float* pa = Aq + (size_t)(row0 + sr) * 1024 + h * 256 + k0 + scc;
                const float* pb = Ak + (size_t)(col0 + sr) * 1024 + h * 256 + k0 + scc;
                unsigned short* da = As_ + sr * 64 + scc;
                unsigned short* db = Bs_ + sr * 64 + scc;
#pragma unroll
                for (int j = 0; j < 8; j++) {
                    float4 va = ((const float4*)pa)[j];
                    float4 vb2 = ((const float4*)pb)[j];
                    ((ushort4*)da)[j] = make_ushort4(f2bf(va.x), f2bf(va.y), f2bf(va.z), f2bf(va.w));
                    ((ushort4*)db)[j] = make_ushort4(f2bf(vb2.x), f2bf(vb2.y), f2bf(vb2.z), f2bf(vb2.w));
                }
            }
            __syncthreads();
#pragma unroll
            for (int kk = 0; kk < 2; kk++) {
                bf16x8 af[4], bfr[4];
#pragma unroll
                for (int f = 0; f < 4; f++) {
                    af[f]  = *(const bf16x8*)(As_ + ((wm * 64 + f * 16 + l15) * 64 + kk * 32 + l16 * 8));
                    bfr[f] = *(const bf16x8*)(Bs_ + ((wn * 64 + f * 16 + l15) * 64 + kk * 32 + l16 * 8));
                }
#pragma unroll
                for (int fi = 0; fi < 4; fi++)
#pragma unroll
                    for (int fj = 0; fj < 4; fj++)
                        acc[fi][fj] = __builtin_amdgcn_mfma_f32_16x16x32_bf16(
                            af[fi], bfr[fj], acc[fi][fj], 0, 0, 0);
            }
        }
#pragma unroll
        for (int fj = 0; fj < 4; fj++) {
            int cc = col0 + wn * 64 + fj * 16 + l15;
#pragma unroll
            for (int fi = 0; fi < 4; fi++) {
                int rbase2 = row0 + wm * 64 + fi * 16 + l16 * 4;
#pragma unroll
                for (int r = 0; r < 4; r++)
                    Wl[(size_t)(h * 256 + rbase2 + r) * 256 + cc] = f2bf(acc[fi][fj][r]);
            }
        }
    } else if (b < 2196) {      // ---- tp (text projection, one block per graph) ----
        float* trow = (float*)sb;               // 3KB alias
        int g = b - 2132;
#pragma unroll
        for (int j = 0; j < 3; j++) trow[t + j * 256] = text[(size_t)g * 768 + t + j * 256];
        __syncthreads();
        float acc = bp[t];
#pragma unroll 4
        for (int k = 0; k < 768; k++) acc += trow[k] * Wp[(size_t)k * 256 + t];
        tp64[(size_t)g * 256 + t] = acc;
    } else if (b < 2212) {      // ---- zero cnt ----
        int i = (b - 2196) * 1024 + t * 4;
        ((int4*)(cnt + i))[0] = make_int4(0, 0, 0, 0);
    } else if (b < 2245) {      // ---- zero pstruct|psem|semden (32832 floats) ----
        int i = (b - 2212) * 1024 + t * 4;
        if (i < 32832)
            ((float4*)(pzero + i))[0] = make_float4(0.f, 0.f, 0.f, 0.f);
    } else if (b < 2253) {      // ---- bv copy ----
        int m = b - 2245, L = m >> 2, chunk = m & 3;
        int i = chunk * 256 + t;
        (ballY + (size_t)L * 2304)[1024 + i] = (bv + (size_t)L * 1024)[i];
    } else {                    // ---- bs copy ----
        int L = b - 2253;
        (ballY + (size_t)L * 2304)[2048 + t] = (bs + (size_t)L * 256)[t];
    }
}

// ---------- scan + graph bounds (single block) ----------
__global__ void scan_kernel(const int* __restrict__ cnt, int* __restrict__ base,
                            int* __restrict__ cursor, const int* __restrict__ bid,
                            int* __restrict__ gstart) {
    int t = threadIdx.x;
    if (t <= 64) {              // fused gbounds (binary search; independent of scan)
        int lo = 0, hi = N_NODES;
        while (lo < hi) { int mid = (lo + hi) >> 1; if (bid[mid] < t) lo = mid + 1; else hi = mid; }
        gstart[t] = lo;
    }
    int s = 0;
    for (int i = 0; i < 64; i++) s += cnt[t * 64 + i];
    __shared__ int pref[256];
    pref[t] = s;
    __syncthreads();
    if (t == 0) {
        int a = 0;
        for (int i = 0; i < 256; i++) { int v = pref[i]; pref[i] = a; a += v; }
    }
    __syncthreads();
    int run = pref[t];
    for (int i = 0; i < 64; i++) {
        base[t * 64 + i] = run;
        cursor[t * 64 + i] = run;
        run += cnt[t * 64 + i];
    }
}

// ---------- XCD-chunked block swizzle (m204 bijective) ----------
__device__ __forceinline__ void swz_block(int& bx, int& by) {
    int nwg = gridDim.x * gridDim.y;
    int lin = blockIdx.y * gridDim.x + blockIdx.x;
    int qd = nwg >> 3, rr = nwg & 7;
    int xcd = lin & 7, j = lin >> 3;
    int wg = (xcd < rr ? xcd * (qd + 1) : rr * (qd + 1) + (xcd - rr) * qd) + j;
    bx = wg % gridDim.x;
    by = wg / gridDim.x;
}

// ---------- MERGED scatter (CSR build) + proj GEMM, block-range dispatch ----------
// [0,256):    scatter (atomic cursor; cursor/esrc visibility via prior dispatch)
// [256,1280): proj 64x64 tiles, 1-TERM (Ahi@Bhi), dbuf, rule-#21 swizzle
__global__ __launch_bounds__(256, 4) void scatter_proj(
        const int* __restrict__ src, const int* __restrict__ dst,
        int* __restrict__ cursor, int* __restrict__ esrc,
        const unsigned short* __restrict__ A, const unsigned short* __restrict__ B,
        const float* __restrict__ bias, float* __restrict__ x,
        unsigned short* __restrict__ xb) {
    __shared__ unsigned short As[2][4096];
    __shared__ unsigned short Bs[2][4096];
    const int tid = threadIdx.x;
    if (blockIdx.x < 256) {     // ---- scatter ----
        int e = blockIdx.x * 256 + tid;
        int d = dst[e];
        int pos = atomicAdd(&cursor[d], 1);
        esrc[pos] = src[e];
        return;
    }
    // ---- proj (1024 logical blocks over 4x256 tile grid, XCD-chunked) ----
    int lin = blockIdx.x - 256;
    int wg = (lin & 7) * 128 + (lin >> 3);      // nwg=1024: qd=128, rr=0
    int bx = wg & 3, by = wg >> 2;
    const int lane = tid & 63, wave = tid >> 6;
    const int wm = wave >> 1, wn = wave & 1;
    const int row0 = by * 64, col0 = bx * 64;
    const int l15 = lane & 15, l16 = lane >> 4;
    f32x4 acc[2][2] = {};
    const char* Ac = (const char*)A;
    const char* Bc = (const char*)B;

#define PSTAGE(BUF, T) do { \
    int k_ = (T) * 128; \
    _Pragma("unroll") \
    for (int i_ = 0; i_ < 2; i_++) { \
        int o_ = i_ * 4096 + tid * 16; \
        int r_ = o_ >> 7, cb_ = o_ & 127; \
        int cs_ = cb_ ^ ((r_ & 7) << 4); \
        GLL(Ac + (size_t)(row0 + r_) * 3072 + k_ + cs_, (char*)As[BUF] + o_); \
        GLL(Bc + (size_t)(col0 + r_) * 4608 + k_ + cs_, (char*)Bs[BUF] + o_); \
    } } while (0)

#define PCOMPUTE(BUF) do { \
    _Pragma("unroll") \
    for (int kk = 0; kk < 2; kk++) { \
        bf16x8 af[2], bfr[2]; \
        _Pragma("unroll") \
        for (int f = 0; f < 2; f++) { \
            int rowa_ = wm * 32 + f * 16 + l15; \
            int qba_ = (kk * 64 + l16 * 16) ^ ((rowa_ & 7) << 4); \
            af[f]  = *(const bf16x8*)((const char*)As[BUF] + rowa_ * 128 + qba_); \
            int rowb_ = wn * 32 + f * 16 + l15; \
            int qbb_ = (kk * 64 + l16 * 16) ^ ((rowb_ & 7) << 4); \
            bfr[f] = *(const bf16x8*)((const char*)Bs[BUF] + rowb_ * 128 + qbb_); \
        } \
        _Pragma("unroll") \
        for (int fi = 0; fi < 2; fi++) \
            _Pragma("unroll") \
            for (int fj = 0; fj < 2; fj++) \
                acc[fi][fj] = __builtin_amdgcn_mfma_f32_16x16x32_bf16( \
                    af[fi], bfr[fj], acc[fi][fj], 0, 0, 0); \
    } } while (0)

    PSTAGE(0, 0);
    __syncthreads();
    for (int t = 0; t < 12; t += 2) {
        PSTAGE(1, t + 1);
        PCOMPUTE(0); __syncthreads();
        if (t + 2 < 12) PSTAGE(0, t + 2);
        PCOMPUTE(1); __syncthreads();
    }
#undef PSTAGE
#undef PCOMPUTE
    // staged coalesced epilogue (f32 + bf16)
    float* smemf = (float*)&As[0][0];   // 64x64 f32 = 16KB
#pragma unroll
    for (int fj = 0; fj < 2; fj++) {
        int cl = wn * 32 + fj * 16 + l15;
        float bb = bias[col0 + cl];
#pragma unroll
        for (int fi = 0; fi < 2; fi++)
#pragma unroll
            for (int r = 0; r < 4; r++) {
                int rl = wm * 32 + fi * 16 + l16 * 4 + r;
                int c16 = cl >> 2;
                smemf[rl * 64 + ((c16 ^ (rl & 15)) << 2) + (cl & 3)] = acc[fi][fj][r] + bb;
            }
    }
    __syncthreads();
    int rl = tid >> 2, q = tid & 3;
#pragma unroll
    for (int i = 0; i < 4; i++) {
        int c16 = q * 4 + i;
        float4 v4 = *(const float4*)&smemf[rl * 64 + ((c16 ^ (rl & 15)) << 2)];
        *(float4*)(x + (size_t)(row0 + rl) * 256 + col0 + c16 * 4) = v4;
        *(ushort4*)(xb + (size_t)(row0 + rl) * 256 + col0 + c16 * 4) =
            make_ushort4(f2bf(v4.x), f2bf(v4.y), f2bf(v4.z), f2bf(v4.w));
    }
}

// ---------- fused YD/v/skip GEMM: [16384,2304] = xin @ Wall^T, 64x64 tiles ----------
// 8 blocks/CU (wave cap), max TLP. Rotation swizzle C-stage (2-way aliasing, free).
__global__ __launch_bounds__(256, 8) void gemm_yvs64t(
        const unsigned short* __restrict__ A, const unsigned short* __restrict__ B,
        const float* __restrict__ ball,
        unsigned short* __restrict__ Yb, unsigned short* __restrict__ vb,
        unsigned short* __restrict__ hb) {
    __shared__ unsigned short smem[8192];       // As(8KB) | Bs(8KB); C-stage reuses 8KB
    unsigned short* As = smem;
    unsigned short* Bs = smem + 4096;
    int bx, by; swz_block(bx, by);
    const int tid = threadIdx.x;
    const int lane = tid & 63, wave = tid >> 6;
    const int wm = wave >> 1, wn = wave & 1;    // 2x2 waves: 32 rows x 32 cols each
    const int row0 = by * 64, col0 = bx * 64;
    const int l15 = lane & 15, l16 = lane >> 4;
    f32x4 acc[2][2] = {};
    const char* Ac = (const char*)A;
    const char* Bc = (const char*)B;

    for (int k0 = 0; k0 < 256; k0 += 64) {
        __syncthreads();
#pragma unroll
        for (int i = 0; i < 2; i++) {           // A+B tiles 8KB each, src pre-swizzled
            int o = i * 4096 + tid * 16;
            int r = o >> 7, cb = o & 127;
            int cs = cb ^ ((r & 7) << 4);
            GLL(Ac + (size_t)(row0 + r) * 512 + k0 * 2 + cs, (char*)As + o);
            GLL(Bc + (size_t)(col0 + r) * 512 + k0 * 2 + cs, (char*)Bs + o);
        }
        __syncthreads();
#pragma unroll
        for (int kk = 0; kk < 2; kk++) {
            bf16x8 af[2], bfr[2];
#pragma unroll
            for (int f = 0; f < 2; f++) {
                int rowa = wm * 32 + f * 16 + l15;
                int qba = (kk * 64 + l16 * 16) ^ ((rowa & 7) << 4);
                af[f] = *(const bf16x8*)((const char*)As + rowa * 128 + qba);
                int rowb = wn * 32 + f * 16 + l15;
                int qbb = (kk * 64 + l16 * 16) ^ ((rowb & 7) << 4);
                bfr[f] = *(const bf16x8*)((const char*)Bs + rowb * 128 + qbb);
            }
#pragma unroll
            for (int fi = 0; fi < 2; fi++)
#pragma unroll
                for (int fj = 0; fj < 2; fj++)
                    acc[fi][fj] = __builtin_amdgcn_mfma_f32_16x16x32_bf16(
                        af[fi], bfr[fj], acc[fi][fj], 0, 0, 0);
        }
    }
    __syncthreads();
    // stage bf16 C-tile (64x64) to LDS with 8-chunk rotation swizzle
#pragma unroll
    for (int fj = 0; fj < 2; fj++) {
        int cl = wn * 32 + fj * 16 + l15;       // local col 0..63
        float bb = ball[col0 + cl];
#pragma unroll
        for (int fi = 0; fi < 2; fi++)
#pragma unroll
            for (int r = 0; r < 4; r++) {
                int rl = wm * 32 + fi * 16 + l16 * 4 + r;   // local row 0..63
                int chunk = ((cl >> 3) + rl) & 7;
                smem[rl * 64 + chunk * 8 + (cl & 7)] = f2bf(acc[fi][fj][r] + bb);
            }
    }
    __syncthreads();
    // coalesced store: 4 threads cover one 128B row
    int rl = tid >> 2, part = tid & 3;
    unsigned short* dstp;
    if (bx < 16)      dstp = Yb + (size_t)(row0 + rl) * 1024 + col0 + part * 16;
    else if (bx < 32) dstp = vb + (size_t)(row0 + rl) * 1024 + (col0 - 1024) + part * 16;
    else              dstp = hb + (size_t)(row0 + rl) * 256 + (col0 - 2048) + part * 16;
#pragma unroll
    for (int i = 0; i < 2; i++) {
        int chunk = (part * 2 + i + rl) & 7;
        ((u16x8*)dstp)[i] = *(const u16x8*)(smem + rl * 64 + chunk * 8);
    }
}

// ---------- fused per-node: scores (YD_d . x_s)/16 + TWO-CHAIN single-pass online
//            softmax + alpha*v gather + head-mean + skip (+resid) + LN + ReLU ----------
template<bool RESID, bool WXB>
__global__ __launch_bounds__(256) void agg_norm_fused(
        const unsigned short* __restrict__ vb, const unsigned short* __restrict__ Yb,
        const int* __restrict__ base, const int* __restrict__ cnt,
        const int* __restrict__ esrc, const unsigned short* __restrict__ hb,
        float* __restrict__ x, const unsigned short* __restrict__ xin,
        unsigned short* __restrict__ xout,
        const float* __restrict__ gamma, const float* __restrict__ beta) {
    __shared__ float hacc[4][256];
    __shared__ float tmp[4];
    // bijective XCD-chunk remap (N_NODES % 8 == 0)
    int n = (blockIdx.x & 7) * (N_NODES >> 3) + (blockIdx.x >> 3);
    int tid = threadIdx.x, lane = tid & 63, h = tid >> 6;
    int start = base[n], deg = cnt[n];

    // own YD row segment (head h), 4 channels per lane
    ushort4 ya = ((const ushort4*)(Yb + (size_t)n * 1024 + h * 256))[lane];
    float y0 = bf2f(ya.x), y1 = bf2f(ya.y), y2 = bf2f(ya.z), y3 = bf2f(ya.w);

    float m0 = -1e30f, den0 = 0.f, m1 = -1e30f, den1 = 0.f;
    float4 acc0 = {0.f, 0.f, 0.f, 0.f}, acc1 = {0.f, 0.f, 0.f, 0.f};
    ushort4 xsA = {0, 0, 0, 0}, vvA = {0, 0, 0, 0};
    ushort4 xsB = {0, 0, 0, 0}, vvB = {0, 0, 0, 0};
    if (deg > 0) {
        int s = esrc[start];
        xsA = ((const ushort4*)(xin + (size_t)s * 256))[lane];
        vvA = ((const ushort4*)(vb + (size_t)s * 1024 + h * 256))[lane];
    }
    if (deg > 1) {
        int s = esrc[start + 1];
        xsB = ((const ushort4*)(xin + (size_t)s * 256))[lane];
        vvB = ((const ushort4*)(vb + (size_t)s * 1024 + h * 256))[lane];
    }
    for (int i = 0; i < deg; i += 2) {
        ushort4 xsA_n = xsA, vvA_n = vvA, xsB_n = xsB, vvB_n = vvB;
        if (i + 2 < deg) {      // prefetch next pair before the reduce chains
            int s = esrc[start + i + 2];
            xsA_n = ((const ushort4*)(xin + (size_t)s * 256))[lane];
            vvA_n = ((const ushort4*)(vb + (size_t)s * 1024 + h * 256))[lane];
        }
        if (i + 3 < deg) {
            int s = esrc[start + i + 3];
            xsB_n = ((const ushort4*)(xin + (size_t)s * 256))[lane];
            vvB_n = ((const ushort4*)(vb + (size_t)s * 1024 + h * 256))[lane];
        }
        float p0 = y0 * bf2f(xsA.x) + y1 * bf2f(xsA.y)
                 + y2 * bf2f(xsA.z) + y3 * bf2f(xsA.w);
        float p1 = y0 * bf2f(xsB.x) + y1 * bf2f(xsB.y)
                 + y2 * bf2f(xsB.z) + y3 * bf2f(xsB.w);
        // two independent butterfly reduces (interleave in the pipe)
#pragma unroll
        for (int off = 32; off; off >>= 1) {
            p0 += __shfl_xor(p0, off);
            p1 += __shfl_xor(p1, off);
        }
        p0 *= 0.0625f; p1 *= 0.0625f;
        // chain 0 (edge i, always valid)
        if (p0 > m0) {
            float sc_ = __expf(m0 - p0);
            den0 = den0 * sc_ + 1.0f;
            acc0.x = acc0.x * sc_ + bf2f(vvA.x);
            acc0.y = acc0.y * sc_ + bf2f(vvA.y);
            acc0.z = acc0.z * sc_ + bf2f(vvA.z);
            acc0.w = acc0.w * sc_ + bf2f(vvA.w);
            m0 = p0;
        } else {
            float a = __expf(p0 - m0);
            den0 += a;
            acc0.x += a * bf2f(vvA.x); acc0.y += a * bf2f(vvA.y);
            acc0.z += a * bf2f(vvA.z); acc0.w += a * bf2f(vvA.w);
        }
        // chain 1 (edge i+1; wave-uniform guard)
        if (i + 1 < deg) {
            if (p1 > m1) {
                float sc_ = __expf(m1 - p1);
                den1 = den1 * sc_ + 1.0f;
                acc1.x = acc1.x * sc_ + bf2f(vvB.x);
                acc1.y = acc1.y * sc_ + bf2f(vvB.y);
                acc1.z = acc1.z * sc_ + bf2f(vvB.z);
                acc1.w = acc1.w * sc_ + bf2f(vvB.w);
                m1 = p1;
            } else {
                float a = __expf(p1 - m1);
                den1 += a;
                acc1.x += a * bf2f(vvB.x); acc1.y += a * bf2f(vvB.y);
                acc1.z += a * bf2f(vvB.z); acc1.w += a * bf2f(vvB.w);
            }
        }
        xsA = xsA_n; vvA = vvA_n; xsB = xsB_n; vvB = vvB_n;
    }
    // exact merge of the two chains (finite sentinels: -1e30 keeps exp args finite)
    float mm = fmaxf(m0, m1);
    float e0 = __expf(m0 - mm), e1 = __expf(m1 - mm);
    float den = den0 * e0 + den1 * e1;
    float4 acc;
    acc.x = acc0.x * e0 + acc1.x * e1;
    acc.y = acc0.y * e0 + acc1.y * e1;
    acc.z = acc0.z * e0 + acc1.z * e1;
    acc.w = acc0.w * e0 + acc1.w * e1;
    float inv_den = 0.25f / (den + 1e-16f);     // fold head-mean
    acc.x *= inv_den; acc.y *= inv_den; acc.z *= inv_den; acc.w *= inv_den;
    ((float4*)&hacc[h][lane * 4])[0] = acc;
    __syncthreads();

    int c = tid;
    float val = hacc[0][c] + hacc[1][c] + hacc[2][c] + hacc[3][c]
              + bf2f(hb[(size_t)n * 256 + c]);
    if (RESID) val += x[(size_t)n * 256 + c];

    float s1 = wave_reduce_sum(val);
    if (lane == 0) tmp[h] = s1;
    __syncthreads();
    float mu = (tmp[0] + tmp[1] + tmp[2] + tmp[3]) * (1.0f / 256.0f);
    __syncthreads();
    float d = val - mu;
    float s2 = wave_reduce_sum(d * d);
    if (lane == 0) tmp[h] = s2;
    __syncthreads();
    float inv = rsqrtf((tmp[0] + tmp[1] + tmp[2] + tmp[3]) * (1.0f / 256.0f) + 1e-5f);
    float o = fmaxf(d * inv * gamma[c] + beta[c], 0.f);
    x[(size_t)n * 256 + c] = o;
    if (WXB) xout[(size_t)n * 256 + c] = f2bf(o);
}

// ---------- fused pooling: struct sums + UNNORMALIZED semantic sums + semden ----------
__global__ __launch_bounds__(256) void pool_seg(
        const float* __restrict__ x, const float* __restrict__ tp,
        const int* __restrict__ gstart, float* __restrict__ pstruct,
        float* __restrict__ psem, float* __restrict__ semden) {
    int g = blockIdx.x >> 2, q = blockIdx.x & 3;
    int s0 = gstart[g], s1 = gstart[g + 1];
    int chunk = (s1 - s0 + 3) >> 2;
    int a = s0 + q * chunk, b = min(a + chunk, s1);
    int wave = threadIdx.x >> 6, lane = threadIdx.x & 63;
    float4 tv = ((const float4*)(tp + (size_t)g * 256))[lane];
    float4 acc = {0.f, 0.f, 0.f, 0.f};
    float4 accs = {0.f, 0.f, 0.f, 0.f};
    float esum = 0.f;
    for (int n = a + wave; n < b; n += 4) {
        float4 xv = ((const float4*)(x + (size_t)n * 256))[lane];
        float p = wave_reduce_sum(xv.x * tv.x + xv.y * tv.y + xv.z * tv.z + xv.w * tv.w);
        float e = __expf(p);            // wave-uniform after reduce
        esum += e;
        acc.x += xv.x; acc.y += xv.y; acc.z += xv.z; acc.w += xv.w;
        accs.x += e * xv.x; accs.y += e * xv.y; accs.z += e * xv.z; accs.w += e * xv.w;
    }
    __shared__ float sacc[4][256];
    __shared__ float sacc2[4][256];
    __shared__ float tse[4];
    ((float4*)&sacc[wave][lane * 4])[0] = acc;
    ((float4*)&sacc2[wave][lane * 4])[0] = accs;
    if (lane == 0) tse[wave] = esum;
    __syncthreads();
    int c = threadIdx.x;
    float v = sacc[0][c] + sacc[1][c] + sacc[2][c] + sacc[3][c];
    float v2 = sacc2[0][c] + sacc2[1][c] + sacc2[2][c] + sacc2[3][c];
    atomicAdd(&pstruct[(size_t)g * 256 + c], v);
    atomicAdd(&psem[(size_t)g * 256 + c], v2);
    if (threadIdx.x == 0)
        atomicAdd(&semden[g], tse[0] + tse[1] + tse[2] + tse[3]);
}

// ---------- classifier (psem unnormalized; divide by semden here) ----------
__global__ void clf_kernel(const float* __restrict__ pstruct, const float* __restrict__ psem,
                           const float* __restrict__ semden,
                           const int* __restrict__ gstart, const float* __restrict__ text,
                           const float* __restrict__ w, const float* __restrict__ b,
                           float* __restrict__ out) {
    int g = blockIdx.x * 4 + (threadIdx.x >> 6);
    int lane = threadIdx.x & 63;
    float invc = 1.0f / fmaxf((float)(gstart[g + 1] - gstart[g]), 1.0f);
    float invs = 1.0f / (semden[g] + 1e-8f);
    float acc = 0.f;
#pragma unroll
    for (int i = 0; i < 4; i++) { int c = lane + i * 64; acc += pstruct[(size_t)g * 256 + c] * invc * w[c]; }
#pragma unroll
    for (int i = 0; i < 4; i++) { int c = lane + i * 64; acc += psem[(size_t)g * 256 + c] * invs * w[256 + c]; }
#pragma unroll
    for (int i = 0; i < 12; i++) { int c = lane + i * 64; acc += text[(size_t)g * 768 + c] * w[512 + c]; }
    acc = wave_reduce_sum(acc);
    if (lane == 0) out[g] = acc + b[0];
}

extern "C" void kernel_launch(void* const* d_in, const int* in_sizes, int n_in,
                              void* d_out, int out_size, void* d_ws, size_t ws_size,
                              hipStream_t stream) {
    const float* text  = (const float*)d_in[0];
    const float* nodex = (const float*)d_in[1];
    const float* Wp    = (const float*)d_in[2];
    const float* bp    = (const float*)d_in[3];
    const float* Wq    = (const float*)d_in[4];
    const float* bq    = (const float*)d_in[5];
    const float* Wk    = (const float*)d_in[6];
    const float* bk    = (const float*)d_in[7];
    const float* Wv    = (const float*)d_in[8];
    const float* bv    = (const float*)d_in[9];
    const float* Ws    = (const float*)d_in[10];
    const float* bs    = (const float*)d_in[11];
    const float* gamma = (const float*)d_in[12];
    const float* beta  = (const float*)d_in[13];
    const float* clfw  = (const float*)d_in[14];
    const float* clfb  = (const float*)d_in[15];
    const int*   eidx  = (const int*)d_in[16];
    const int*   bid   = (const int*)d_in[17];
    const int* src = eidx;
    const int* dst = eidx + N_EDGES;
    float* out = (float*)d_out;

    // workspace layout
    float* x     = (float*)d_ws;                     // 16384*256 f32
    float* tp64  = x + (size_t)N_NODES * 256;        // 64*256
    float* pstruct = tp64 + 64 * 256;                // 64*256
    float* psem  = pstruct + 64 * 256;               // 64*256
    float* semden = psem + 64 * 256;                 // 64
    float* ballY = semden + 64;                      // 2*2304
    int* esrc    = (int*)(ballY + 2 * 2304);         // 65536
    int* cnt     = esrc + N_EDGES;                   // 16384
    int* base    = cnt + N_NODES;                    // 16384
    int* cursor  = base + N_NODES;                   // 16384
    int* gstart  = cursor + N_NODES;                 // 80 (65 used)
    unsigned short* Yb   = (unsigned short*)(gstart + 80);  // 16384*1024 bf16
    unsigned short* vb   = Yb + (size_t)N_NODES * 1024;     // 16384*1024
    unsigned short* hb   = vb + (size_t)N_NODES * 1024;     // 16384*256
    unsigned short* xb   = hb + (size_t)N_NODES * 256;      // 16384*256
    unsigned short* xb2  = xb + (size_t)N_NODES * 256;      // 16384*256 (layer-1 input)
    unsigned short* Wall = xb2 + (size_t)N_NODES * 256;     // 2*2304*256
    unsigned short* Wps  = Wall + (size_t)2 * 2304 * 256;   // 256*2304
    // nfs [16384,1536] aliases Yb(+part of vb); consumed by proj before those are written
    unsigned short* nfs = Yb;

    // MEGA prep: Wps + Wall/ballY + M^T + tp64 + zero(cnt) + zero(pools) in ONE dispatch
    prep_mega<<<2255, 256, 0, stream>>>(Wp, Wq, Wk, Wv, Ws, bq, bk, bv, bs, text, bp,
                                        Wps, Wall, ballY, tp64, cnt, pstruct);
    // relevance + node features + edge histogram (cnt zeroed upstream)
    relnf_kernel<<<N_NODES, 256, 0, stream>>>(text, nodex, bid, dst, nfs, cnt);
    // scan + graph bounds (single block)
    scan_kernel<<<1, 256, 0, stream>>>(cnt, base, cursor, bid, gstart);
    // merged scatter (CSR) + projection GEMM (emits x f32 + xb bf16)
    scatter_proj<<<1280, 256, 0, stream>>>(src, dst, cursor, esrc,
                                           nfs, Wps, bp, x, xb);

    for (int i = 0; i < 2; i++) {
        const unsigned short* xin = (i == 0) ? xb : xb2;
        // fused YD/v/skip GEMM (K=256, 64x64 tiles, 8 blocks/CU, rotation-swizzled C-stage)
        gemm_yvs64t<<<dim3(36, N_NODES / 64), 256, 0, stream>>>(
            xin, Wall + (size_t)i * 2304 * 256, ballY + i * 2304, Yb, vb, hb);
        // fused scores + two-chain softmax + gather + head-mean + skip + (resid) + LN + ReLU
        if (i == 0)
            agg_norm_fused<true, true><<<N_NODES, 256, 0, stream>>>(
                vb, Yb, base, cnt, esrc, hb, x, xin, xb2, gamma, beta);
        else
            agg_norm_fused<false, false><<<N_NODES, 256, 0, stream>>>(
                vb, Yb, base, cnt, esrc, hb, x, xin, xb2, gamma + 256, beta + 256);
    }

    // single fused pool pass (pools zeroed by prep_mega)
    pool_seg<<<N_GRAPHS * 4, 256, 0, stream>>>(x, tp64, gstart, pstruct, psem, semden);
    clf_kernel<<<N_GRAPHS / 4, 256, 0, stream>>>(pstruct, psem, semden, gstart, text,
                                                 clfw, clfb, out);
}